// Round 15
// baseline (31552.795 us; speedup 1.0000x reference)
//
#include <hip/hip_runtime.h>

#define T_STEPS  8192
#define INPUT_N  256
#define OUTPUT_N 256
#define RES_N    4096
#define NB       256   // blocks (1 per CU)
#define NT       1024  // threads per block (16 waves)
#define RPB      16    // rows per block

#define PIN(x) asm volatile("" : "+v"(x))
#define PINU4(v) do { PIN((v).x); PIN((v).y); PIN((v).z); PIN((v).w); } while (0)

typedef unsigned long long ull;
typedef _Float16 half2v __attribute__((ext_vector_type(2)));

// f32x2 -> packed f16x2 (v_cvt_pkrtz_f16_f32), as raw dword.
__device__ __forceinline__ unsigned pkf16(float lo, float hi) {
    return __builtin_bit_cast(unsigned, __builtin_amdgcn_cvt_pkrtz(lo, hi));
}
// acc += dot(f16x2 w, f16x2 s)  (v_dot2_f32_f16, f32 accumulate)
__device__ __forceinline__ float fdot2(unsigned w, unsigned s, float acc) {
    return __builtin_amdgcn_fdot2(__builtin_bit_cast(half2v, w),
                                  __builtin_bit_cast(half2v, s), acc, false);
}
// tanh via native exp + fast div: 1 - 2/(e^{2x}+1). |err| ~1e-6.
__device__ __forceinline__ float fast_tanh(float x) {
    const float e = __expf(2.0f * x);
    return 1.0f - __fdividef(2.0f, e + 1.0f);
}

// Persistent ESN: f16 LDS weights + dot2 MAC + self-flagging state exchange
// (R12 cross-block protocol, UNTOUCHED) + R15: barrier-free intra-block
// reduction with a DYNAMIC last-finisher publisher.
//
// R15 change (intra-block only):
//   - deposits: lane<16 unsafeAtomicAdd into lds_acc[par][row] (ds_add_f32,
//     16 distinct addrs = conflict-free) instead of lds_part writes.
//   - each wave: deposits -> s_waitcnt lgkmcnt(0) -> ds_add_rtn on
//     lds_cnt[par]. The wave seeing old == 16*(t/2)+15 is the LAST
//     depositor: it reads the 16 finished sums (1 dword/lane), fast_tanh,
//     and issues the SAME coalesced 64B tagged publish, then zeroes acc.
//   - NO per-step __syncthreads: other waves fall through to their next
//     spin. Hazard ordering via the cnt chain:
//       * acc overwrite (t+2 vs read at t): deposits at t+2 require
//         spin(t+2) <= our publish(t+1) <= cnt(t+1)==16 incl. publisher-
//         of-t's deposit(t+1), which follows its zero-of-par_t.
//       * lds_pp[ppar] read by wave14 at t vs overwrite at t+1: the READ
//         is issued before wave14's cnt-add of step t; writes at t+1
//         require publish(t) <= cnt(t)==16 incl. wave14's add.
//       * publisher's acc read sees all adds: every wave drains lgkmcnt
//         before its cnt add, and cnt==target implies all 16 drained.
//
// Exchange (proven R8/R10/R12): stbuf[2][4096] dwords; dword i of parity
// p = f16(state[i]) | (t+1)<<16 — the tag IS the flag. Consumer lane spins
// on its own 4 data dwords (min tag >= t), s_sleep backoff. Publish = ONE
// 64B wave-store (R11 lesson). Lap-proof by transitivity. stbuf zeroed
// per call (graph replay).
__global__ __launch_bounds__(NT)
void esn_persistent(
    const float* __restrict__ X,       // [T, 256]
    const float* __restrict__ state0,  // [4096]
    const float* __restrict__ W_in,    // [4096, 256]
    const float* __restrict__ W_res,   // [4096, 4096]
    const float* __restrict__ W_out,   // [256, 4096]
    float* __restrict__ out,           // [T, 256]
    unsigned* __restrict__ stbuf)      // ws: [2][4096] tagged, zeroed per call
{
    const int tid  = threadIdx.x;
    const int bid  = blockIdx.x;
    const int wid  = tid >> 6;
    const int lane = tid & 63;
    const int qg   = lane >> 2;
    const int rg   = lane & 3;
    const int cg   = wid * 16 + qg;

    __shared__ unsigned w_lds[2 * 16 * 4 * 64 * 4];  // 128 KB f16x2 weights
    __shared__ float    lds_acc[2][16];              // per-parity row sums
    __shared__ float    lds_pp[2][16];               // per-wave pred partials
    __shared__ unsigned lds_cnt[2];                  // monotonic deposit counters

    // ---- one-time: zero reduction state ----
    if (tid < 2) lds_cnt[tid] = 0u;
    if (tid < 32) lds_acc[tid >> 4][tid & 15] = 0.f;

    // ---- one-time: weights -> f16 pairs in LDS / registers ----
    float win[4];
#pragma unroll
    for (int r = 0; r < 4; ++r) {
        const int grow = bid * RPB + 4 * rg + r;
#pragma unroll
        for (int c = 0; c < 2; ++c) {
            const float* wr = W_res + (size_t)grow * RES_N + c * 2048 + 8 * cg;
            const float4 a = *(const float4*)wr;
            const float4 b = *(const float4*)(wr + 4);
            uint4 pk;
            pk.x = pkf16(a.x, a.y);
            pk.y = pkf16(a.z, a.w);
            pk.z = pkf16(b.x, b.y);
            pk.w = pkf16(b.z, b.w);
            ((uint4*)w_lds)[((c * 16 + wid) * 4 + r) * 64 + lane] = pk;
        }
        win[r] = W_in[(size_t)grow * INPUT_N + cg];
        PIN(win[r]);
    }
    unsigned wo[8];
#pragma unroll
    for (int m = 0; m < 8; ++m) {
        const int col = (m < 4) ? (8 * cg + 2 * m) : (2048 + 8 * cg + 2 * (m - 4));
        wo[m] = pkf16(W_out[(size_t)bid * RES_N + col],
                      W_out[(size_t)bid * RES_N + col + 1]);
        PIN(wo[m]);
    }
    __syncthreads();  // one-time: weights + zeroed acc/cnt visible

    // This lane's quarter-slice offset (4 consecutive state cols).
    const int ofs_base = ((rg < 2) ? (8 * cg) : (2048 + 8 * cg)) + 4 * (rg & 1);

    float xv = X[cg];  // x_0[cg]

#pragma unroll 1
    for (int t = 0; t <= T_STEPS; ++t) {
        const int par  = t & 1;
        const int ppar = (t + 1) & 1;

        // ---- weight prefetch: state-independent ds_reads issue BEFORE the
        // spin; their latency hides under the wait. PIN pins them live. ----
        uint4 w[2][4];
#pragma unroll
        for (int c = 0; c < 2; ++c)
#pragma unroll
            for (int r = 0; r < 4; ++r) {
                w[c][r] = ((const uint4*)w_lds)[(((c * 16 + wid) * 4 + r) * 64) + lane];
                PINU4(w[c][r]);
            }

        // ---- acquire 4 tagged dwords of state_{t-1} (s_sleep backoff) ----
        unsigned d0, d1, d2, d3;
        if (t == 0) {
            const float4 q = *(const float4*)(state0 + ofs_base);
            d0 = pkf16(q.x, 0.f);
            d1 = pkf16(q.y, 0.f);
            d2 = pkf16(q.z, 0.f);
            d3 = pkf16(q.w, 0.f);
        } else {
            const unsigned exp = (unsigned)t;  // state_{t-1} tagged t
            const ull* sp = (const ull*)(stbuf + (size_t)ppar * RES_N + ofs_base);
            for (;;) {
                const ull lo = __hip_atomic_load(sp, __ATOMIC_RELAXED,
                                                 __HIP_MEMORY_SCOPE_AGENT);
                const ull hi = __hip_atomic_load(sp + 1, __ATOMIC_RELAXED,
                                                 __HIP_MEMORY_SCOPE_AGENT);
                d0 = (unsigned)lo; d1 = (unsigned)(lo >> 32);
                d2 = (unsigned)hi; d3 = (unsigned)(hi >> 32);
                const unsigned tmin =
                    min(min(d0 >> 16, d1 >> 16), min(d2 >> 16, d3 >> 16));
                if (tmin >= exp) break;
                __builtin_amdgcn_s_sleep(1);  // decongest L3 poll traffic
            }
        }

        // prefetch next x (hidden under shuffles/MAC)
        const float xn = X[(size_t)((t + 1 < T_STEPS) ? (t + 1) : 0) * INPUT_N + cg];

        // ---- wave14: issue the pred-partial read for out[t-2] NOW (must
        // precede this wave's cnt-add; see hazard notes above) ----
        float pv = 0.f;
        const bool do_out = (t >= 2 && wid == 14);
        if (do_out && lane < 16) pv = lds_pp[ppar][lane];

        // ---- strip tags into f16x2 pairs, broadcast across the quad ----
        const unsigned pl0 = __builtin_amdgcn_perm(d1, d0, 0x05040100u);
        const unsigned pl1 = __builtin_amdgcn_perm(d3, d2, 0x05040100u);
        unsigned sp16[8];
#pragma unroll
        for (int m = 0; m < 8; ++m)
            sp16[m] = __shfl((m & 1) ? pl1 : pl0, (lane & 0x3C) | (m >> 1), 64);

        // ---- MAC: 4 rows x 8 dot2 on prefetched weights ----
        if (t < T_STEPS) {
            float p0 = win[0] * xv, p1 = win[1] * xv;
            float p2 = win[2] * xv, p3 = win[3] * xv;
#pragma unroll
            for (int c = 0; c < 2; ++c) {
                const unsigned s0 = sp16[4 * c + 0], s1 = sp16[4 * c + 1];
                const unsigned s2 = sp16[4 * c + 2], s3 = sp16[4 * c + 3];
                p0 = fdot2(w[c][0].x, s0, p0); p0 = fdot2(w[c][0].y, s1, p0);
                p0 = fdot2(w[c][0].z, s2, p0); p0 = fdot2(w[c][0].w, s3, p0);
                p1 = fdot2(w[c][1].x, s0, p1); p1 = fdot2(w[c][1].y, s1, p1);
                p1 = fdot2(w[c][1].z, s2, p1); p1 = fdot2(w[c][1].w, s3, p1);
                p2 = fdot2(w[c][2].x, s0, p2); p2 = fdot2(w[c][2].y, s1, p2);
                p2 = fdot2(w[c][2].z, s2, p2); p2 = fdot2(w[c][2].w, s3, p2);
                p3 = fdot2(w[c][3].x, s0, p3); p3 = fdot2(w[c][3].y, s1, p3);
                p3 = fdot2(w[c][3].z, s2, p3); p3 = fdot2(w[c][3].w, s3, p3);
            }
            // merged reduce over the 16 same-rg lanes (stride-4)
            p0 += __shfl_xor(p0, 4, 64); p1 += __shfl_xor(p1, 4, 64);
            p2 += __shfl_xor(p2, 4, 64); p3 += __shfl_xor(p3, 4, 64);
            p0 += __shfl_xor(p0, 8, 64); p1 += __shfl_xor(p1, 8, 64);
            p2 += __shfl_xor(p2, 8, 64); p3 += __shfl_xor(p3, 8, 64);
            float v = (qg & 1) ? ((qg & 2) ? p3 : p1)
                               : ((qg & 2) ? p2 : p0);
            v += __shfl_xor(v, 16, 64);
            v += __shfl_xor(v, 32, 64);
            if (lane < 16)  // deposit row 4*(l&3)+(l>>2) via native ds_add_f32
                unsafeAtomicAdd(&lds_acc[par][4 * (lane & 3) + (lane >> 2)], v);
        }

        // ---- pred partial for state_{t-1} (deposit before cnt) ----
        if (t > 0) {
            float pp = 0.f;
            if (rg == 0) {
#pragma unroll
                for (int m = 0; m < 8; ++m) pp = fdot2(wo[m], sp16[m], pp);
            }
            pp += __shfl_xor(pp, 4, 64);
            pp += __shfl_xor(pp, 8, 64);
            pp += __shfl_xor(pp, 16, 64);
            pp += __shfl_xor(pp, 32, 64);
            if (lane == 0) lds_pp[par][wid] = pp;
        }

        // ---- deposit fence + last-finisher detection ----
        if (t < T_STEPS) {
            asm volatile("s_waitcnt lgkmcnt(0)" ::: "memory");  // adds committed
            unsigned old = 0;
            if (lane == 0) old = atomicAdd(&lds_cnt[par], 1u);
            old = __shfl(old, 0, 64);
            if (old == 16u * (unsigned)(t >> 1) + 15u) {
                // LAST depositor: all 16 waves' sums are in lds_acc[par].
                if (lane < 16) {
                    const float s = lds_acc[par][lane];
                    const float ns = fast_tanh(s);
                    const unsigned dw = pkf16(ns, 0.f) | ((unsigned)(t + 1) << 16);
                    // 16 lanes, consecutive dwords: ONE coalesced 64B store
                    __hip_atomic_store(stbuf + (size_t)par * RES_N + bid * RPB + lane,
                                       dw, __ATOMIC_RELAXED, __HIP_MEMORY_SCOPE_AGENT);
                    lds_acc[par][lane] = 0.f;  // re-arm before own t+1 deposit
                }
            }
        }

        // ---- wave14: finish pred reduce -> out[t-2] (post-critical) ----
        if (do_out) {
            pv += __shfl_xor(pv, 8, 64);
            pv += __shfl_xor(pv, 4, 64);
            pv += __shfl_xor(pv, 2, 64);
            pv += __shfl_xor(pv, 1, 64);
            if (lane == 0) out[(size_t)(t - 2) * OUTPUT_N + bid] = pv;
        }

        xv = xn;
    }

    // ---- epilogue: out[T-1] from iteration T's pred partials ----
    __syncthreads();
    if (wid == 14 && lane < 16) {
        float pv = lds_pp[T_STEPS & 1][lane];
        pv += __shfl_xor(pv, 8, 64);
        pv += __shfl_xor(pv, 4, 64);
        pv += __shfl_xor(pv, 2, 64);
        pv += __shfl_xor(pv, 1, 64);
        if (lane == 0) out[(size_t)(T_STEPS - 1) * OUTPUT_N + bid] = pv;
    }
}

extern "C" void kernel_launch(void* const* d_in, const int* in_sizes, int n_in,
                              void* d_out, int out_size, void* d_ws, size_t ws_size,
                              hipStream_t stream) {
    const float* X      = (const float*)d_in[0];
    const float* state0 = (const float*)d_in[1];
    const float* W_in   = (const float*)d_in[2];
    const float* W_res  = (const float*)d_in[3];
    const float* W_out  = (const float*)d_in[4];
    float* out = (float*)d_out;

    unsigned* stbuf = (unsigned*)d_ws;  // 2*4096 tagged dwords = 32 KiB

    // Tags must start below any expected value every call (graph replays
    // reuse d_ws without re-poisoning; stale tags would satisfy the spin).
    (void)hipMemsetAsync(stbuf, 0, 2 * RES_N * sizeof(unsigned), stream);

    esn_persistent<<<dim3(NB), dim3(NT), 0, stream>>>(
        X, state0, W_in, W_res, W_out, out, stbuf);
}

// Round 16
// 17593.216 us; speedup vs baseline: 1.7935x; 1.7935x over previous
//
#include <hip/hip_runtime.h>

#define T_STEPS  8192
#define INPUT_N  256
#define OUTPUT_N 256
#define RES_N    4096
#define NB       256   // blocks (1 per CU)
#define NT       1024  // threads per block (16 waves)
#define RPB      16    // rows per block

#define PIN(x) asm volatile("" : "+v"(x))
#define PINU4(v) do { PIN((v).x); PIN((v).y); PIN((v).z); PIN((v).w); } while (0)

typedef unsigned long long ull;
typedef _Float16 half2v __attribute__((ext_vector_type(2)));

// f32x2 -> packed f16x2 (v_cvt_pkrtz_f16_f32), as raw dword.
__device__ __forceinline__ unsigned pkf16(float lo, float hi) {
    return __builtin_bit_cast(unsigned, __builtin_amdgcn_cvt_pkrtz(lo, hi));
}
// acc += dot(f16x2 w, f16x2 s)  (v_dot2_f32_f16, f32 accumulate)
__device__ __forceinline__ float fdot2(unsigned w, unsigned s, float acc) {
    return __builtin_amdgcn_fdot2(__builtin_bit_cast(half2v, w),
                                  __builtin_bit_cast(half2v, s), acc, false);
}
// tanh via native exp + fast div: 1 - 2/(e^{2x}+1). |err| ~1e-6.
__device__ __forceinline__ float fast_tanh(float x) {
    const float e = __expf(2.0f * x);
    return 1.0f - __fdividef(2.0f, e + 1.0f);
}

// Persistent ESN: f16 LDS weights + dot2 MAC + self-flagging state exchange.
// EXACT R12 state — best proven (17.57 ms, reproduced twice: R12, R14).
//
// Exchange-structure change ledger (5/5 regressed — do not touch):
//   R6/R7  acquire/threadfence cache ops (buffer_inv/wbl2): +70%
//   R11    distributed per-wave publish: WRITE x5.7, staggered vis: +20%
//   R13    rotating publisher + poll-first: FETCH +40%: +17%
//   R15    barrier-free last-finisher (lds_cnt chain): free-running waves
//          -> poll-miss FETCH x1.75, LDS-atomic serialization: +80%
// Proven-good structure: block-aggregate (lds_part, 1 barrier) -> wave15
// ONE coalesced 64B tagged publish -> all-to-all fine-grained L3 spin
// (relaxed sc1 atomics only, s_sleep backoff, weight-prefetch under spin).
//
// Exchange: stbuf[2][4096] dwords; dword i of parity p =
// f16(state[i]) | (t+1)<<16 — the tag IS the flag. Consumer lane spins on
// its own 4 data dwords (min tag >= t). Lap-proof by transitivity (every
// block consumes every block's slice every step). stbuf zeroed per call.
//
// Step (1 barrier): prefetch weights (ds_read issues under spin) -> spin
// (s_sleep backoff) -> tag-strip + quad-broadcast (8 f16x2) -> MAC (32
// dot2) + merged reduce -> lds_part[par][row][wid] (stride 20) ->
// syncthreads -> wave15: 4xb128 combine + fast_tanh + coalesced 64B
// tagged publish; wave14: reduce lds_pp[ppar] -> out[t-2]; all: pred
// partial -> lds_pp[par] (off critical path).
__global__ __launch_bounds__(NT)
void esn_persistent(
    const float* __restrict__ X,       // [T, 256]
    const float* __restrict__ state0,  // [4096]
    const float* __restrict__ W_in,    // [4096, 256]
    const float* __restrict__ W_res,   // [4096, 4096]
    const float* __restrict__ W_out,   // [256, 4096]
    float* __restrict__ out,           // [T, 256]
    unsigned* __restrict__ stbuf)      // ws: [2][4096] tagged, zeroed per call
{
    const int tid  = threadIdx.x;
    const int bid  = blockIdx.x;
    const int wid  = tid >> 6;
    const int lane = tid & 63;
    const int qg   = lane >> 2;
    const int rg   = lane & 3;
    const int cg   = wid * 16 + qg;

    __shared__ unsigned w_lds[2 * 16 * 4 * 64 * 4];  // 128 KB f16x2 weights
    __shared__ float lds_part[2][16][20];            // [par][row][wid], pad 20
    __shared__ float lds_pp[2][16];

    // ---- one-time: weights -> f16 pairs in LDS / registers ----
    float win[4];
#pragma unroll
    for (int r = 0; r < 4; ++r) {
        const int grow = bid * RPB + 4 * rg + r;
#pragma unroll
        for (int c = 0; c < 2; ++c) {
            const float* wr = W_res + (size_t)grow * RES_N + c * 2048 + 8 * cg;
            const float4 a = *(const float4*)wr;
            const float4 b = *(const float4*)(wr + 4);
            uint4 pk;
            pk.x = pkf16(a.x, a.y);
            pk.y = pkf16(a.z, a.w);
            pk.z = pkf16(b.x, b.y);
            pk.w = pkf16(b.z, b.w);
            ((uint4*)w_lds)[((c * 16 + wid) * 4 + r) * 64 + lane] = pk;
        }
        win[r] = W_in[(size_t)grow * INPUT_N + cg];
        PIN(win[r]);
    }
    unsigned wo[8];
#pragma unroll
    for (int m = 0; m < 8; ++m) {
        const int col = (m < 4) ? (8 * cg + 2 * m) : (2048 + 8 * cg + 2 * (m - 4));
        wo[m] = pkf16(W_out[(size_t)bid * RES_N + col],
                      W_out[(size_t)bid * RES_N + col + 1]);
        PIN(wo[m]);
    }

    // This lane's quarter-slice offset (4 consecutive state cols).
    const int ofs_base = ((rg < 2) ? (8 * cg) : (2048 + 8 * cg)) + 4 * (rg & 1);

    float xv = X[cg];  // x_0[cg]

#pragma unroll 1
    for (int t = 0; t <= T_STEPS; ++t) {
        const int par  = t & 1;
        const int ppar = (t + 1) & 1;

        // ---- weight prefetch: state-independent ds_reads issue BEFORE the
        // spin; their latency hides under the wait. PIN pins them live. ----
        uint4 w[2][4];
#pragma unroll
        for (int c = 0; c < 2; ++c)
#pragma unroll
            for (int r = 0; r < 4; ++r) {
                w[c][r] = ((const uint4*)w_lds)[(((c * 16 + wid) * 4 + r) * 64) + lane];
                PINU4(w[c][r]);
            }

        // ---- acquire 4 tagged dwords of state_{t-1} (s_sleep backoff) ----
        unsigned d0, d1, d2, d3;
        if (t == 0) {
            const float4 q = *(const float4*)(state0 + ofs_base);
            d0 = pkf16(q.x, 0.f);
            d1 = pkf16(q.y, 0.f);
            d2 = pkf16(q.z, 0.f);
            d3 = pkf16(q.w, 0.f);
        } else {
            const unsigned exp = (unsigned)t;  // state_{t-1} tagged t
            const ull* sp = (const ull*)(stbuf + (size_t)ppar * RES_N + ofs_base);
            for (;;) {
                const ull lo = __hip_atomic_load(sp, __ATOMIC_RELAXED,
                                                 __HIP_MEMORY_SCOPE_AGENT);
                const ull hi = __hip_atomic_load(sp + 1, __ATOMIC_RELAXED,
                                                 __HIP_MEMORY_SCOPE_AGENT);
                d0 = (unsigned)lo; d1 = (unsigned)(lo >> 32);
                d2 = (unsigned)hi; d3 = (unsigned)(hi >> 32);
                const unsigned tmin =
                    min(min(d0 >> 16, d1 >> 16), min(d2 >> 16, d3 >> 16));
                if (tmin >= exp) break;
                __builtin_amdgcn_s_sleep(1);  // decongest L3 poll traffic
            }
        }

        // prefetch next x (hidden under shuffles/MAC)
        const float xn = X[(size_t)((t + 1 < T_STEPS) ? (t + 1) : 0) * INPUT_N + cg];

        // ---- strip tags into f16x2 pairs, broadcast across the quad ----
        const unsigned pl0 = __builtin_amdgcn_perm(d1, d0, 0x05040100u);
        const unsigned pl1 = __builtin_amdgcn_perm(d3, d2, 0x05040100u);
        unsigned sp16[8];
#pragma unroll
        for (int m = 0; m < 8; ++m)
            sp16[m] = __shfl((m & 1) ? pl1 : pl0, (lane & 0x3C) | (m >> 1), 64);

        // ---- MAC: 4 rows x 8 dot2 on prefetched weights ----
        if (t < T_STEPS) {
            float p0 = win[0] * xv, p1 = win[1] * xv;
            float p2 = win[2] * xv, p3 = win[3] * xv;
#pragma unroll
            for (int c = 0; c < 2; ++c) {
                const unsigned s0 = sp16[4 * c + 0], s1 = sp16[4 * c + 1];
                const unsigned s2 = sp16[4 * c + 2], s3 = sp16[4 * c + 3];
                p0 = fdot2(w[c][0].x, s0, p0); p0 = fdot2(w[c][0].y, s1, p0);
                p0 = fdot2(w[c][0].z, s2, p0); p0 = fdot2(w[c][0].w, s3, p0);
                p1 = fdot2(w[c][1].x, s0, p1); p1 = fdot2(w[c][1].y, s1, p1);
                p1 = fdot2(w[c][1].z, s2, p1); p1 = fdot2(w[c][1].w, s3, p1);
                p2 = fdot2(w[c][2].x, s0, p2); p2 = fdot2(w[c][2].y, s1, p2);
                p2 = fdot2(w[c][2].z, s2, p2); p2 = fdot2(w[c][2].w, s3, p2);
                p3 = fdot2(w[c][3].x, s0, p3); p3 = fdot2(w[c][3].y, s1, p3);
                p3 = fdot2(w[c][3].z, s2, p3); p3 = fdot2(w[c][3].w, s3, p3);
            }
            // merged reduce over the 16 same-rg lanes (stride-4)
            p0 += __shfl_xor(p0, 4, 64); p1 += __shfl_xor(p1, 4, 64);
            p2 += __shfl_xor(p2, 4, 64); p3 += __shfl_xor(p3, 4, 64);
            p0 += __shfl_xor(p0, 8, 64); p1 += __shfl_xor(p1, 8, 64);
            p2 += __shfl_xor(p2, 8, 64); p3 += __shfl_xor(p3, 8, 64);
            float v = (qg & 1) ? ((qg & 2) ? p3 : p1)
                               : ((qg & 2) ? p2 : p0);
            v += __shfl_xor(v, 16, 64);
            v += __shfl_xor(v, 32, 64);
            if (lane < 16)
                lds_part[par][4 * (lane & 3) + (lane >> 2)][wid] = v;  // [row][w]
        }
        __syncthreads();  // the only per-step barrier

        // ---- wave 15: b128 combine + fast_tanh + COALESCED tagged publish ----
        if (t < T_STEPS && wid == 15 && lane < 16) {
            const float4 a = *(const float4*)(&lds_part[par][lane][0]);
            const float4 b = *(const float4*)(&lds_part[par][lane][4]);
            const float4 c = *(const float4*)(&lds_part[par][lane][8]);
            const float4 d = *(const float4*)(&lds_part[par][lane][12]);
            const float s = ((a.x + a.y) + (a.z + a.w)) + ((b.x + b.y) + (b.z + b.w))
                          + ((c.x + c.y) + (c.z + c.w)) + ((d.x + d.y) + (d.z + d.w));
            const float ns = fast_tanh(s);
            const unsigned dw = pkf16(ns, 0.f) | ((unsigned)(t + 1) << 16);
            // 16 lanes, consecutive dwords: one 64B store -> atomic visibility
            __hip_atomic_store(stbuf + (size_t)par * RES_N + bid * RPB + lane,
                               dw, __ATOMIC_RELAXED, __HIP_MEMORY_SCOPE_AGENT);
        }

        // ---- wave 14: delayed pred reduce -> out[t-2] ----
        if (t >= 2 && wid == 14 && lane < 16) {
            float pv = lds_pp[ppar][lane];
            pv += __shfl_xor(pv, 8, 64);
            pv += __shfl_xor(pv, 4, 64);
            pv += __shfl_xor(pv, 2, 64);
            pv += __shfl_xor(pv, 1, 64);
            if (lane == 0) out[(size_t)(t - 2) * OUTPUT_N + bid] = pv;
        }

        // ---- pred partial for state_{t-1} (off critical path) ----
        if (t > 0) {
            float pp = 0.f;
            if (rg == 0) {
#pragma unroll
                for (int m = 0; m < 8; ++m) pp = fdot2(wo[m], sp16[m], pp);
            }
            pp += __shfl_xor(pp, 4, 64);
            pp += __shfl_xor(pp, 8, 64);
            pp += __shfl_xor(pp, 16, 64);
            pp += __shfl_xor(pp, 32, 64);
            if (lane == 0) lds_pp[par][wid] = pp;
        }

        xv = xn;
    }

    // ---- epilogue: out[T-1] from iteration T's pred partials ----
    __syncthreads();
    if (wid == 14 && lane < 16) {
        float pv = lds_pp[T_STEPS & 1][lane];
        pv += __shfl_xor(pv, 8, 64);
        pv += __shfl_xor(pv, 4, 64);
        pv += __shfl_xor(pv, 2, 64);
        pv += __shfl_xor(pv, 1, 64);
        if (lane == 0) out[(size_t)(T_STEPS - 1) * OUTPUT_N + bid] = pv;
    }
}

extern "C" void kernel_launch(void* const* d_in, const int* in_sizes, int n_in,
                              void* d_out, int out_size, void* d_ws, size_t ws_size,
                              hipStream_t stream) {
    const float* X      = (const float*)d_in[0];
    const float* state0 = (const float*)d_in[1];
    const float* W_in   = (const float*)d_in[2];
    const float* W_res  = (const float*)d_in[3];
    const float* W_out  = (const float*)d_in[4];
    float* out = (float*)d_out;

    unsigned* stbuf = (unsigned*)d_ws;  // 2*4096 tagged dwords = 32 KiB

    // Tags must start below any expected value every call (graph replays
    // reuse d_ws without re-poisoning; stale tags would satisfy the spin).
    (void)hipMemsetAsync(stbuf, 0, 2 * RES_N * sizeof(unsigned), stream);

    esn_persistent<<<dim3(NB), dim3(NT), 0, stream>>>(
        X, state0, W_in, W_res, W_out, out, stbuf);
}